// Round 2
// baseline (193.756 us; speedup 1.0000x reference)
//
#include <hip/hip_runtime.h>
#include <hip/hip_bf16.h>
#include <stdint.h>
#include <type_traits>

typedef __bf16 bf16;
typedef __bf16 bf16x4 __attribute__((ext_vector_type(4)));
typedef __bf16 bf16x8 __attribute__((ext_vector_type(8)));
typedef float floatx4 __attribute__((ext_vector_type(4)));
typedef unsigned int u32;
typedef u32 u32x4 __attribute__((ext_vector_type(4)));

#define D_MODEL 1024
#define SEQ 2048
#define NHEADS 16
#define DH 64
#define BATCH 2
#define MROWS (BATCH * SEQ)  // 4096

#define XELEMS ((size_t)MROWS * D_MODEL)
#define WELEMS ((size_t)D_MODEL * D_MODEL)
#define CVT_ELEMS (XELEMS + 4 * WELEMS)

__device__ __forceinline__ void gload_lds16(const void* g, void* l) {
  __builtin_amdgcn_global_load_lds(
      (const __attribute__((address_space(1))) u32*)g,
      (__attribute__((address_space(3))) u32*)l, 16, 0, 0);
}

// ---------------------------------------------------------------------------
// One-shot f32 -> bf16 convert of X + 4 weights (~57 MB traffic, mem-bound).
// ---------------------------------------------------------------------------
__global__ __launch_bounds__(256) void cvt_f32_bf16(
    const float* __restrict__ s0, const float* __restrict__ s1,
    const float* __restrict__ s2, const float* __restrict__ s3,
    const float* __restrict__ s4, bf16* __restrict__ dst) {
  const size_t i = ((size_t)blockIdx.x * 256 + threadIdx.x) * 8;
  const float* src;
  size_t off;
  if (i < XELEMS) {
    src = s0; off = i;
  } else {
    const size_t j = i - XELEMS;
    const int r = (int)(j / WELEMS);
    src = (r == 0) ? s1 : (r == 1) ? s2 : (r == 2) ? s3 : s4;
    off = j - (size_t)r * WELEMS;
  }
  floatx4 f0 = *(const floatx4*)&src[off];
  floatx4 f1 = *(const floatx4*)&src[off + 4];
  bf16x8 o;
#pragma unroll
  for (int j = 0; j < 4; j++) { o[j] = (bf16)f0[j]; o[4 + j] = (bf16)f1[j]; }
  *(bf16x8*)&dst[i] = o;
}

// ---------------------------------------------------------------------------
// Merged QKV GEMM v2 (unchanged from round 1): single GEMM over concatenated
// W = [Wq|Wk|Wv] (3072x1024).  BM=256 x BN=128, BK=64, 8 waves, 3-slot LDS
// ring staged two K-tiles ahead with counted vmcnt(6) across raw barriers.
// ---------------------------------------------------------------------------
#define QKV_ASLOT (256 * 64)            // 16384 elems = 32 KB
#define QKV_SLOT  (256 * 64 + 128 * 64) // 24576 elems = 48 KB

__global__ __launch_bounds__(512) void gemm_qkv(
    const bf16* __restrict__ A, const bf16* __restrict__ W,
    bf16* __restrict__ Qo, bf16* __restrict__ Ko, bf16* __restrict__ Vto) {
  __shared__ bf16 sm[3 * QKV_SLOT];     // 147456 B

  const int tid = threadIdx.x;
  const int lane = tid & 63;
  const int w = tid >> 6;        // 0..7
  const int lo16 = lane & 15;
  const int quad = lane >> 4;
  const int wy = w >> 1;         // 0..3 : 64-row band of the 256-row tile
  const int wx = w & 1;          // 0..1 : 64-col band of the 128-col tile

  const int n0 = blockIdx.x * 128;   // 0..2944 (concat feature dim, 3072)
  const int m0 = blockIdx.y * 256;   // token-row tile

  const int sl = lane >> 3;
  const int sc = ((lane & 7) ^ sl) * 8;   // pre-swizzled global column

  const floatx4 fz = {0.f, 0.f, 0.f, 0.f};
  floatx4 acc[4][4];
#pragma unroll
  for (int i = 0; i < 4; i++)
#pragma unroll
    for (int j = 0; j < 4; j++) acc[i][j] = fz;

  auto stage = [&](int t, int s) {
    bf16* As = &sm[s * QKV_SLOT];
    bf16* Bs = As + QKV_ASLOT;
    const int k0 = t * 64;
#pragma unroll
    for (int i = 0; i < 4; i++) {
      const int seg = w * 4 + i;              // 0..31 (256 A rows)
      const int row = seg * 8 + sl;
      gload_lds16(&A[(size_t)(m0 + row) * 1024 + k0 + sc], &As[seg * 512]);
    }
#pragma unroll
    for (int i = 0; i < 2; i++) {
      const int seg = w * 2 + i;              // 0..15 (128 W rows)
      const int row = seg * 8 + sl;
      gload_lds16(&W[(size_t)(n0 + row) * 1024 + k0 + sc], &Bs[seg * 512]);
    }
  };

  auto compute = [&](int s, auto vt) {
    constexpr bool VT = decltype(vt)::value;
    const bf16* As = &sm[s * QKV_SLOT];
    const bf16* Bs = As + QKV_ASLOT;
#pragma unroll
    for (int kk = 0; kk < 64; kk += 32) {
      bf16x8 af[4], bfr[4];
      const int cc = (kk >> 3) + quad;
#pragma unroll
      for (int t = 0; t < 4; t++) {
        const int ra = wy * 64 + t * 16 + lo16;   // 0..255
        const int rb = wx * 64 + t * 16 + lo16;   // 0..127
        af[t]  = *(const bf16x8*)&As[ra * 64 + ((cc ^ (ra & 7)) << 3)];
        bfr[t] = *(const bf16x8*)&Bs[rb * 64 + ((cc ^ (rb & 7)) << 3)];
      }
#pragma unroll
      for (int mt = 0; mt < 4; mt++)
#pragma unroll
        for (int nt = 0; nt < 4; nt++) {
          if constexpr (VT)
            acc[mt][nt] = __builtin_amdgcn_mfma_f32_16x16x32_bf16(bfr[nt], af[mt], acc[mt][nt], 0, 0, 0);
          else
            acc[mt][nt] = __builtin_amdgcn_mfma_f32_16x16x32_bf16(af[mt], bfr[nt], acc[mt][nt], 0, 0, 0);
        }
    }
  };

  auto step = [&](int t, int s, auto vt) {
    if (t + 2 < 16) stage(t + 2, (t + 2) % 3);
    compute(s, vt);
    if (t < 15) {
      if (t + 2 < 16) { asm volatile("s_waitcnt vmcnt(6)" ::: "memory"); }
      else            { asm volatile("s_waitcnt vmcnt(0)" ::: "memory"); }
      __builtin_amdgcn_s_barrier();
    }
  };

  auto mainloop = [&](auto vt) {
    stage(0, 0);
    stage(1, 1);
    asm volatile("s_waitcnt vmcnt(6)" ::: "memory");
    __builtin_amdgcn_s_barrier();
    for (int tb = 0; tb < 15; tb += 3) {
      step(tb + 0, 0, vt);
      step(tb + 1, 1, vt);
      step(tb + 2, 2, vt);
    }
    step(15, 0, vt);   // tail: no wait/barrier
  };
  if (n0 >= 2048) mainloop(std::true_type{}); else mainloop(std::false_type{});

  if (n0 < 2048) {
    bf16* C = (n0 < 1024) ? Qo : Ko;
    const int nc = (n0 < 1024) ? n0 : n0 - 1024;
#pragma unroll
    for (int mt = 0; mt < 4; mt++)
#pragma unroll
      for (int nt = 0; nt < 4; nt++)
#pragma unroll
        for (int r = 0; r < 4; r++) {
          const int row = m0 + wy * 64 + mt * 16 + quad * 4 + r;
          const int col = nc + wx * 64 + nt * 16 + lo16;
          C[(size_t)row * D_MODEL + col] = (bf16)acc[mt][nt][r];
        }
  } else {
    const int nv = n0 - 2048;
#pragma unroll
    for (int mt = 0; mt < 4; mt++)
#pragma unroll
      for (int nt = 0; nt < 4; nt++)
#pragma unroll
        for (int r = 0; r < 4; r++) {
          const int feat = nv + wx * 64 + nt * 16 + quad * 4 + r;
          const int tok  = m0 + wy * 64 + mt * 16 + lo16;
          const int hh = feat >> 6, dd = feat & 63;
          const int bb = tok >> 11, ss = tok & 2047;
          Vto[(size_t)((bb * NHEADS + hh) * DH + dd) * SEQ + ss] = (bf16)acc[mt][nt][r];
        }
  }
}

// ---------------------------------------------------------------------------
// O-projection GEMM (unchanged): 64x128 tile, BK=128 as two BK=64 halves,
// XOR swizzle, f32 out.
// ---------------------------------------------------------------------------
__global__ __launch_bounds__(256) void gemm_o(
    const bf16* __restrict__ A, const bf16* __restrict__ W,
    float* __restrict__ C) {
  __shared__ bf16 As[2 * 64 * 64];
  __shared__ bf16 Bs[2 * 128 * 64];

  const int tid = threadIdx.x;
  const int lane = tid & 63;
  const int w = tid >> 6;
  const int lo16 = lane & 15;
  const int quad = lane >> 4;
  const int wy = w >> 1, wx = w & 1;

  const int m0 = blockIdx.y * 64;
  const int n0 = blockIdx.x * 128;

  const int sl = lane >> 3;
  const int sc = ((lane & 7) ^ sl) * 8;

  const floatx4 fz = {0.f, 0.f, 0.f, 0.f};
  floatx4 acc[2][4];
#pragma unroll
  for (int i = 0; i < 2; i++)
#pragma unroll
    for (int j = 0; j < 4; j++) acc[i][j] = fz;

  for (int k0 = 0; k0 < 1024; k0 += 128) {
    __syncthreads();
#pragma unroll
    for (int kh = 0; kh < 2; kh++) {
#pragma unroll
      for (int i = 0; i < 2; i++) {
        const int seg = i * 4 + w;
        const int row = seg * 8 + sl;
        gload_lds16(&A[(size_t)(m0 + row) * 1024 + k0 + kh * 64 + sc],
                    &As[kh * 4096 + seg * 512]);
      }
#pragma unroll
      for (int i = 0; i < 4; i++) {
        const int seg = i * 4 + w;
        const int row = seg * 8 + sl;
        gload_lds16(&W[(size_t)(n0 + row) * 1024 + k0 + kh * 64 + sc],
                    &Bs[kh * 8192 + seg * 512]);
      }
    }
    __syncthreads();

#pragma unroll
    for (int kk = 0; kk < 128; kk += 32) {
      const int kh = kk >> 6;
      const int cc = ((kk & 63) >> 3) + quad;
      bf16x8 af[2], bfr[4];
#pragma unroll
      for (int t = 0; t < 2; t++) {
        const int ra = wy * 32 + t * 16 + lo16;
        af[t] = *(const bf16x8*)&As[kh * 4096 + ra * 64 + ((cc ^ (ra & 7)) << 3)];
      }
#pragma unroll
      for (int t = 0; t < 4; t++) {
        const int rb = wx * 64 + t * 16 + lo16;
        bfr[t] = *(const bf16x8*)&Bs[kh * 8192 + rb * 64 + ((cc ^ (rb & 7)) << 3)];
      }
#pragma unroll
      for (int mt = 0; mt < 2; mt++)
#pragma unroll
        for (int nt = 0; nt < 4; nt++)
          acc[mt][nt] = __builtin_amdgcn_mfma_f32_16x16x32_bf16(af[mt], bfr[nt], acc[mt][nt], 0, 0, 0);
    }
  }

#pragma unroll
  for (int mt = 0; mt < 2; mt++)
#pragma unroll
    for (int nt = 0; nt < 4; nt++)
#pragma unroll
      for (int r = 0; r < 4; r++) {
        const int row = m0 + wy * 32 + mt * 16 + quad * 4 + r;
        const int col = n0 + wx * 64 + nt * 16 + lo16;
        C[(size_t)row * D_MODEL + col] = acc[mt][nt][r];
      }
}

// ---------------------------------------------------------------------------
// Causal flash attention v8: one 64-row q-tile per block (grid 32x16x2 =
// 1024 blocks, heavy-first qt = 31-x for LPT scheduling).  8 waves: g = kv
// half of the 128-chunk, w4 = q-quarter.  P never touches LDS: after swapped
// QK^T (S^T in regs), v_cvt_pk_bf16_f32 + permlane32/16_swap redistribute
// P into the PV A-fragment layout in-register (T12).  LDS = Ks + VTs only
// (35840 B); epilogue combine aliased with stride 21 (bank-conflict-free).
// ---------------------------------------------------------------------------
#define LPK 72    // Ks row stride (bf16): 128 rows
#define LPV 136   // VTs row stride (bf16): 64 rows x 128 kv cols

__global__ __launch_bounds__(512, 6) void attn_causal(
    const bf16* __restrict__ Q, const bf16* __restrict__ Kg,
    const bf16* __restrict__ Vt, bf16* __restrict__ O) {
  __shared__ __align__(16) char smem[35840];
  bf16* Ks  = (bf16*)smem;              // 128*72*2  = 18432 B
  bf16* VTs = (bf16*)(smem + 18432);    // 64*136*2  = 17408 B
  float* Es = (float*)smem;             // epilogue alias: 256*21*4 = 21504 B

  const int tid = threadIdx.x;
  const int lane = tid & 63;
  const int wid = tid >> 6;      // 0..7
  const int g = wid >> 2;        // kv-half of the 128-chunk
  const int w4 = wid & 3;        // q-quarter
  const int lo16 = lane & 15;
  const int quad = lane >> 4;

  const int qt = 31 - blockIdx.x;   // heavy-first dispatch
  const int n = (qt + 2) >> 1;      // 128-chunks needed
  const int h = blockIdx.y;
  const int b = blockIdx.z;
  const size_t base  = (size_t)b * SEQ * D_MODEL + (size_t)h * DH;
  const size_t baset = (size_t)(b * NHEADS + h) * DH * SEQ;

  const int rq = qt * 64 + w4 * 16 + lo16;
  bf16x8 qf[2];
#pragma unroll
  for (int ks = 0; ks < 2; ks++)
    qf[ks] = *(const bf16x8*)&Q[base + (size_t)rq * D_MODEL + ks * 32 + quad * 8];

  bf16x8 onesf;
#pragma unroll
  for (int j = 0; j < 8; j++) onesf[j] = (bf16)1.0f;

  const floatx4 fz = {0.f, 0.f, 0.f, 0.f};
  floatx4 oacc[4];
  floatx4 lacc = fz;
#pragma unroll
  for (int i = 0; i < 4; i++) oacc[i] = fz;

  // staging indices: K chunk 128x64 (2 rows/thread), V chunk 64x128 (2 halves)
  const int kr = tid >> 3;        // 0..63
  const int kc = (tid & 7) * 8;

  bf16x8 kvp[2], vvp[2];
#pragma unroll
  for (int c2 = 0; c2 < 2; c2++) {
    kvp[c2] = *(const bf16x8*)&Kg[base + (size_t)(c2 * 64 + kr) * D_MODEL + kc];
    vvp[c2] = *(const bf16x8*)&Vt[baset + (size_t)kr * SEQ + c2 * 64 + kc];
  }

  for (int c = 0; c < n; c++) {
    const int j0 = c * 128;
    __syncthreads();
#pragma unroll
    for (int c2 = 0; c2 < 2; c2++) {
      *(bf16x8*)&Ks[(c2 * 64 + kr) * LPK + kc] = kvp[c2];
      *(bf16x8*)&VTs[kr * LPV + c2 * 64 + kc] = vvp[c2];
    }
    __syncthreads();

    if (c + 1 < n) {
      const int j1 = j0 + 128;
#pragma unroll
      for (int c2 = 0; c2 < 2; c2++) {
        kvp[c2] = *(const bf16x8*)&Kg[base + (size_t)(j1 + c2 * 64 + kr) * D_MODEL + kc];
        vvp[c2] = *(const bf16x8*)&Vt[baset + (size_t)kr * SEQ + j1 + c2 * 64 + kc];
      }
    }

    // QK^T (swapped: S^T in regs, lane holds P[k=n4*16+quad*4+r][q=lo16])
    floatx4 sacc[4];
#pragma unroll
    for (int n4 = 0; n4 < 4; n4++) sacc[n4] = fz;
#pragma unroll
    for (int n4 = 0; n4 < 4; n4++) {
      const int rk = g * 64 + n4 * 16 + lo16;
#pragma unroll
      for (int ks = 0; ks < 2; ks++) {
        bf16x8 kf = *(const bf16x8*)&Ks[rk * LPK + ks * 32 + quad * 8];
        sacc[n4] = __builtin_amdgcn_mfma_f32_16x16x32_bf16(kf, qf[ks], sacc[n4], 0, 0, 0);
      }
    }

    // softmax: p = 2^(s*0.18033688 - 17.3123405) (shift-invariant), pack to
    // bf16 words wv[n4][p] = (P[k=16n4+4q+2p], P[k=..+1]) for this lane.
    u32 wv[4][2];
    if (c == n - 1) {
      const int myq = rq;
#pragma unroll
      for (int n4 = 0; n4 < 4; n4++) {
        float e[4];
#pragma unroll
        for (int r = 0; r < 4; r++) {
          const int kvb = j0 + g * 64 + n4 * 16 + quad * 4 + r;
          const float ev = __builtin_amdgcn_exp2f(fmaf(sacc[n4][r], 0.18033688f, -17.3123405f));
          e[r] = (kvb > myq) ? 0.f : ev;
        }
        asm("v_cvt_pk_bf16_f32 %0, %1, %2" : "=v"(wv[n4][0]) : "v"(e[0]), "v"(e[1]));
        asm("v_cvt_pk_bf16_f32 %0, %1, %2" : "=v"(wv[n4][1]) : "v"(e[2]), "v"(e[3]));
      }
    } else {
#pragma unroll
      for (int n4 = 0; n4 < 4; n4++) {
        float e[4];
#pragma unroll
        for (int r = 0; r < 4; r++)
          e[r] = __builtin_amdgcn_exp2f(fmaf(sacc[n4][r], 0.18033688f, -17.3123405f));
        asm("v_cvt_pk_bf16_f32 %0, %1, %2" : "=v"(wv[n4][0]) : "v"(e[0]), "v"(e[1]));
        asm("v_cvt_pk_bf16_f32 %0, %1, %2" : "=v"(wv[n4][1]) : "v"(e[2]), "v"(e[3]));
      }
    }

    // in-register transpose to PV A-fragment: word(n4,p)@quad s must land at
    // dest quad t=2*(n4&1)+(s>>1), slot 2*(s&1)+p, half ks=n4>>1.
    // permlane32_swap then permlane16_swap on (w[2ks][p], w[2ks+1][p])
    // yields (slot p, slot 2+p) simultaneously.
#pragma unroll
    for (int ks = 0; ks < 2; ks++) {
      u32 a0 = wv[2 * ks][0], b0 = wv[2 * ks + 1][0];
      u32 a1 = wv[2 * ks][1], b1 = wv[2 * ks + 1][1];
      asm("v_permlane32_swap_b32 %0, %1" : "+v"(a0), "+v"(b0));
      asm("v_permlane16_swap_b32 %0, %1" : "+v"(a0), "+v"(b0));
      asm("v_permlane32_swap_b32 %0, %1" : "+v"(a1), "+v"(b1));
      asm("v_permlane16_swap_b32 %0, %1" : "+v"(a1), "+v"(b1));
      u32x4 fw = {a0, a1, b0, b1};
      const bf16x8 pf = __builtin_bit_cast(bf16x8, fw);
#pragma unroll
      for (int dt = 0; dt < 4; dt++) {
        bf16x8 vf = *(const bf16x8*)&VTs[(dt * 16 + lo16) * LPV + g * 64 + ks * 32 + quad * 8];
        oacc[dt] = __builtin_amdgcn_mfma_f32_16x16x32_bf16(pf, vf, oacc[dt], 0, 0, 0);
      }
      lacc = __builtin_amdgcn_mfma_f32_16x16x32_bf16(pf, onesf, lacc, 0, 0, 0);
    }
  }

  // epilogue: combine kv-half partials (additive; fixed shift).  Es aliases
  // the staging LDS, so drain all loop-phase LDS reads first.  Stride 21
  // floats: gcd(21,32)=1 -> 2 lanes/bank, conflict-free.
  __syncthreads();
  if (g == 1) {
    float* e = &Es[(w4 * 64 + lane) * 21];
#pragma unroll
    for (int dt = 0; dt < 4; dt++)
#pragma unroll
      for (int r = 0; r < 4; r++) e[dt * 4 + r] = oacc[dt][r];
#pragma unroll
    for (int r = 0; r < 4; r++) e[16 + r] = lacc[r];
  }
  __syncthreads();
  if (g == 0) {
    const float* e = &Es[(w4 * 64 + lane) * 21];
#pragma unroll
    for (int dt = 0; dt < 4; dt++)
#pragma unroll
      for (int r = 0; r < 4; r++) oacc[dt][r] += e[dt * 4 + r];
#pragma unroll
    for (int r = 0; r < 4; r++) lacc[r] += e[16 + r];

#pragma unroll
    for (int r = 0; r < 4; r++) {
      const float inv = 1.0f / lacc[r];
      const int row = qt * 64 + w4 * 16 + quad * 4 + r;
#pragma unroll
      for (int dt = 0; dt < 4; dt++)
        O[base + (size_t)row * D_MODEL + dt * 16 + lo16] = (bf16)(oacc[dt][r] * inv);
    }
  }
}

extern "C" void kernel_launch(void* const* d_in, const int* in_sizes, int n_in,
                              void* d_out, int out_size, void* d_ws, size_t ws_size,
                              hipStream_t stream) {
  const float* X  = (const float*)d_in[0];
  const float* Wq = (const float*)d_in[1];
  const float* Wk = (const float*)d_in[2];
  const float* Wv = (const float*)d_in[3];
  const float* Wo = (const float*)d_in[4];
  float* out = (float*)d_out;

  bf16* cvt = (bf16*)d_ws;
  bf16* Xb  = cvt;
  bf16* Wqb = cvt + XELEMS;       // Wq|Wk|Wv contiguous => concat [3072x1024]
  bf16* Wob = Wqb + 3 * WELEMS;
  bf16* Qb  = cvt + CVT_ELEMS;
  bf16* Kb  = Qb + XELEMS;
  bf16* Vtb = Kb + XELEMS;        // [B][H][DH][SEQ]
  bf16* Ob  = Vtb + XELEMS;

  dim3 blk(256);
  cvt_f32_bf16<<<dim3((u32)(CVT_ELEMS / (256 * 8))), blk, 0, stream>>>(
      X, Wq, Wk, Wv, Wo, cvt);
  gemm_qkv<<<dim3(24, 16), dim3(512), 0, stream>>>(Xb, Wqb, Qb, Kb, Vtb);
  attn_causal<<<dim3(32, NHEADS, BATCH), dim3(512), 0, stream>>>(Qb, Kb, Vtb, Ob);
  gemm_o<<<dim3(8, 64), blk, 0, stream>>>(Ob, Wob, out);
}

// Round 3
// 183.478 us; speedup vs baseline: 1.0560x; 1.0560x over previous
//
#include <hip/hip_runtime.h>
#include <hip/hip_bf16.h>
#include <stdint.h>
#include <type_traits>

typedef __bf16 bf16;
typedef __bf16 bf16x4 __attribute__((ext_vector_type(4)));
typedef __bf16 bf16x8 __attribute__((ext_vector_type(8)));
typedef float floatx4 __attribute__((ext_vector_type(4)));
typedef unsigned int u32;
typedef u32 u32x4 __attribute__((ext_vector_type(4)));

#define D_MODEL 1024
#define SEQ 2048
#define NHEADS 16
#define DH 64
#define BATCH 2
#define MROWS (BATCH * SEQ)  // 4096

#define XELEMS ((size_t)MROWS * D_MODEL)
#define WELEMS ((size_t)D_MODEL * D_MODEL)
#define CVT_ELEMS (XELEMS + 4 * WELEMS)

__device__ __forceinline__ void gload_lds16(const void* g, void* l) {
  __builtin_amdgcn_global_load_lds(
      (const __attribute__((address_space(1))) u32*)g,
      (__attribute__((address_space(3))) u32*)l, 16, 0, 0);
}

// ---------------------------------------------------------------------------
// One-shot f32 -> bf16 convert of X + 4 weights (~57 MB traffic, mem-bound).
// ---------------------------------------------------------------------------
__global__ __launch_bounds__(256) void cvt_f32_bf16(
    const float* __restrict__ s0, const float* __restrict__ s1,
    const float* __restrict__ s2, const float* __restrict__ s3,
    const float* __restrict__ s4, bf16* __restrict__ dst) {
  const size_t i = ((size_t)blockIdx.x * 256 + threadIdx.x) * 8;
  const float* src;
  size_t off;
  if (i < XELEMS) {
    src = s0; off = i;
  } else {
    const size_t j = i - XELEMS;
    const int r = (int)(j / WELEMS);
    src = (r == 0) ? s1 : (r == 1) ? s2 : (r == 2) ? s3 : s4;
    off = j - (size_t)r * WELEMS;
  }
  floatx4 f0 = *(const floatx4*)&src[off];
  floatx4 f1 = *(const floatx4*)&src[off + 4];
  bf16x8 o;
#pragma unroll
  for (int j = 0; j < 4; j++) { o[j] = (bf16)f0[j]; o[4 + j] = (bf16)f1[j]; }
  *(bf16x8*)&dst[i] = o;
}

// ---------------------------------------------------------------------------
// Merged QKV GEMM v2 (unchanged): single GEMM over concatenated
// W = [Wq|Wk|Wv] (3072x1024).  BM=256 x BN=128, BK=64, 8 waves, 3-slot LDS
// ring staged two K-tiles ahead with counted vmcnt(6) across raw barriers.
// ---------------------------------------------------------------------------
#define QKV_ASLOT (256 * 64)            // 16384 elems = 32 KB
#define QKV_SLOT  (256 * 64 + 128 * 64) // 24576 elems = 48 KB

__global__ __launch_bounds__(512) void gemm_qkv(
    const bf16* __restrict__ A, const bf16* __restrict__ W,
    bf16* __restrict__ Qo, bf16* __restrict__ Ko, bf16* __restrict__ Vto) {
  __shared__ bf16 sm[3 * QKV_SLOT];     // 147456 B

  const int tid = threadIdx.x;
  const int lane = tid & 63;
  const int w = tid >> 6;        // 0..7
  const int lo16 = lane & 15;
  const int quad = lane >> 4;
  const int wy = w >> 1;         // 0..3 : 64-row band of the 256-row tile
  const int wx = w & 1;          // 0..1 : 64-col band of the 128-col tile

  const int n0 = blockIdx.x * 128;   // 0..2944 (concat feature dim, 3072)
  const int m0 = blockIdx.y * 256;   // token-row tile

  const int sl = lane >> 3;
  const int sc = ((lane & 7) ^ sl) * 8;   // pre-swizzled global column

  const floatx4 fz = {0.f, 0.f, 0.f, 0.f};
  floatx4 acc[4][4];
#pragma unroll
  for (int i = 0; i < 4; i++)
#pragma unroll
    for (int j = 0; j < 4; j++) acc[i][j] = fz;

  auto stage = [&](int t, int s) {
    bf16* As = &sm[s * QKV_SLOT];
    bf16* Bs = As + QKV_ASLOT;
    const int k0 = t * 64;
#pragma unroll
    for (int i = 0; i < 4; i++) {
      const int seg = w * 4 + i;              // 0..31 (256 A rows)
      const int row = seg * 8 + sl;
      gload_lds16(&A[(size_t)(m0 + row) * 1024 + k0 + sc], &As[seg * 512]);
    }
#pragma unroll
    for (int i = 0; i < 2; i++) {
      const int seg = w * 2 + i;              // 0..15 (128 W rows)
      const int row = seg * 8 + sl;
      gload_lds16(&W[(size_t)(n0 + row) * 1024 + k0 + sc], &Bs[seg * 512]);
    }
  };

  auto compute = [&](int s, auto vt) {
    constexpr bool VT = decltype(vt)::value;
    const bf16* As = &sm[s * QKV_SLOT];
    const bf16* Bs = As + QKV_ASLOT;
#pragma unroll
    for (int kk = 0; kk < 64; kk += 32) {
      bf16x8 af[4], bfr[4];
      const int cc = (kk >> 3) + quad;
#pragma unroll
      for (int t = 0; t < 4; t++) {
        const int ra = wy * 64 + t * 16 + lo16;   // 0..255
        const int rb = wx * 64 + t * 16 + lo16;   // 0..127
        af[t]  = *(const bf16x8*)&As[ra * 64 + ((cc ^ (ra & 7)) << 3)];
        bfr[t] = *(const bf16x8*)&Bs[rb * 64 + ((cc ^ (rb & 7)) << 3)];
      }
#pragma unroll
      for (int mt = 0; mt < 4; mt++)
#pragma unroll
        for (int nt = 0; nt < 4; nt++) {
          if constexpr (VT)
            acc[mt][nt] = __builtin_amdgcn_mfma_f32_16x16x32_bf16(bfr[nt], af[mt], acc[mt][nt], 0, 0, 0);
          else
            acc[mt][nt] = __builtin_amdgcn_mfma_f32_16x16x32_bf16(af[mt], bfr[nt], acc[mt][nt], 0, 0, 0);
        }
    }
  };

  auto step = [&](int t, int s, auto vt) {
    if (t + 2 < 16) stage(t + 2, (t + 2) % 3);
    compute(s, vt);
    if (t < 15) {
      if (t + 2 < 16) { asm volatile("s_waitcnt vmcnt(6)" ::: "memory"); }
      else            { asm volatile("s_waitcnt vmcnt(0)" ::: "memory"); }
      __builtin_amdgcn_s_barrier();
    }
  };

  auto mainloop = [&](auto vt) {
    stage(0, 0);
    stage(1, 1);
    asm volatile("s_waitcnt vmcnt(6)" ::: "memory");
    __builtin_amdgcn_s_barrier();
    for (int tb = 0; tb < 15; tb += 3) {
      step(tb + 0, 0, vt);
      step(tb + 1, 1, vt);
      step(tb + 2, 2, vt);
    }
    step(15, 0, vt);   // tail: no wait/barrier
  };
  if (n0 >= 2048) mainloop(std::true_type{}); else mainloop(std::false_type{});

  if (n0 < 2048) {
    bf16* C = (n0 < 1024) ? Qo : Ko;
    const int nc = (n0 < 1024) ? n0 : n0 - 1024;
#pragma unroll
    for (int mt = 0; mt < 4; mt++)
#pragma unroll
      for (int nt = 0; nt < 4; nt++)
#pragma unroll
        for (int r = 0; r < 4; r++) {
          const int row = m0 + wy * 64 + mt * 16 + quad * 4 + r;
          const int col = nc + wx * 64 + nt * 16 + lo16;
          C[(size_t)row * D_MODEL + col] = (bf16)acc[mt][nt][r];
        }
  } else {
    const int nv = n0 - 2048;
#pragma unroll
    for (int mt = 0; mt < 4; mt++)
#pragma unroll
      for (int nt = 0; nt < 4; nt++)
#pragma unroll
        for (int r = 0; r < 4; r++) {
          const int feat = nv + wx * 64 + nt * 16 + quad * 4 + r;
          const int tok  = m0 + wy * 64 + mt * 16 + lo16;
          const int hh = feat >> 6, dd = feat & 63;
          const int bb = tok >> 11, ss = tok & 2047;
          Vto[(size_t)((bb * NHEADS + hh) * DH + dd) * SEQ + ss] = (bf16)acc[mt][nt][r];
        }
  }
}

// ---------------------------------------------------------------------------
// O-projection GEMM (unchanged): 64x128 tile, BK=128 as two BK=64 halves,
// XOR swizzle, f32 out.
// ---------------------------------------------------------------------------
__global__ __launch_bounds__(256) void gemm_o(
    const bf16* __restrict__ A, const bf16* __restrict__ W,
    float* __restrict__ C) {
  __shared__ bf16 As[2 * 64 * 64];
  __shared__ bf16 Bs[2 * 128 * 64];

  const int tid = threadIdx.x;
  const int lane = tid & 63;
  const int w = tid >> 6;
  const int lo16 = lane & 15;
  const int quad = lane >> 4;
  const int wy = w >> 1, wx = w & 1;

  const int m0 = blockIdx.y * 64;
  const int n0 = blockIdx.x * 128;

  const int sl = lane >> 3;
  const int sc = ((lane & 7) ^ sl) * 8;

  const floatx4 fz = {0.f, 0.f, 0.f, 0.f};
  floatx4 acc[2][4];
#pragma unroll
  for (int i = 0; i < 2; i++)
#pragma unroll
    for (int j = 0; j < 4; j++) acc[i][j] = fz;

  for (int k0 = 0; k0 < 1024; k0 += 128) {
    __syncthreads();
#pragma unroll
    for (int kh = 0; kh < 2; kh++) {
#pragma unroll
      for (int i = 0; i < 2; i++) {
        const int seg = i * 4 + w;
        const int row = seg * 8 + sl;
        gload_lds16(&A[(size_t)(m0 + row) * 1024 + k0 + kh * 64 + sc],
                    &As[kh * 4096 + seg * 512]);
      }
#pragma unroll
      for (int i = 0; i < 4; i++) {
        const int seg = i * 4 + w;
        const int row = seg * 8 + sl;
        gload_lds16(&W[(size_t)(n0 + row) * 1024 + k0 + kh * 64 + sc],
                    &Bs[kh * 8192 + seg * 512]);
      }
    }
    __syncthreads();

#pragma unroll
    for (int kk = 0; kk < 128; kk += 32) {
      const int kh = kk >> 6;
      const int cc = ((kk & 63) >> 3) + quad;
      bf16x8 af[2], bfr[4];
#pragma unroll
      for (int t = 0; t < 2; t++) {
        const int ra = wy * 32 + t * 16 + lo16;
        af[t] = *(const bf16x8*)&As[kh * 4096 + ra * 64 + ((cc ^ (ra & 7)) << 3)];
      }
#pragma unroll
      for (int t = 0; t < 4; t++) {
        const int rb = wx * 64 + t * 16 + lo16;
        bfr[t] = *(const bf16x8*)&Bs[kh * 8192 + rb * 64 + ((cc ^ (rb & 7)) << 3)];
      }
#pragma unroll
      for (int mt = 0; mt < 2; mt++)
#pragma unroll
        for (int nt = 0; nt < 4; nt++)
          acc[mt][nt] = __builtin_amdgcn_mfma_f32_16x16x32_bf16(af[mt], bfr[nt], acc[mt][nt], 0, 0, 0);
    }
  }

#pragma unroll
  for (int mt = 0; mt < 2; mt++)
#pragma unroll
    for (int nt = 0; nt < 4; nt++)
#pragma unroll
      for (int r = 0; r < 4; r++) {
        const int row = m0 + wy * 32 + mt * 16 + quad * 4 + r;
        const int col = n0 + wx * 64 + nt * 16 + lo16;
        C[(size_t)row * D_MODEL + col] = acc[mt][nt][r];
      }
}

// ---------------------------------------------------------------------------
// Causal flash attention v9: v8 structure (one 64-row q-tile per block,
// grid 32x16x2 heavy-first, in-register P via cvt_pk + permlane swaps,
// LDS = Ks+VTs = 35840 B) with the spill-inducing launch_bounds(512,6)
// reverted to the v7-proven (512,4).  With ~44 persistent VGPRs the
// allocator should land <=64 naturally -> 4 blocks/CU (LDS allows 4).
// ---------------------------------------------------------------------------
#define LPK 72    // Ks row stride (bf16): 128 rows
#define LPV 136   // VTs row stride (bf16): 64 rows x 128 kv cols

__global__ __launch_bounds__(512, 4) void attn_causal(
    const bf16* __restrict__ Q, const bf16* __restrict__ Kg,
    const bf16* __restrict__ Vt, bf16* __restrict__ O) {
  __shared__ __align__(16) char smem[35840];
  bf16* Ks  = (bf16*)smem;              // 128*72*2  = 18432 B
  bf16* VTs = (bf16*)(smem + 18432);    // 64*136*2  = 17408 B
  float* Es = (float*)smem;             // epilogue alias: 256*21*4 = 21504 B

  const int tid = threadIdx.x;
  const int lane = tid & 63;
  const int wid = tid >> 6;      // 0..7
  const int g = wid >> 2;        // kv-half of the 128-chunk
  const int w4 = wid & 3;        // q-quarter
  const int lo16 = lane & 15;
  const int quad = lane >> 4;

  const int qt = 31 - blockIdx.x;   // heavy-first dispatch
  const int n = (qt + 2) >> 1;      // 128-chunks needed
  const int h = blockIdx.y;
  const int b = blockIdx.z;
  const size_t base  = (size_t)b * SEQ * D_MODEL + (size_t)h * DH;
  const size_t baset = (size_t)(b * NHEADS + h) * DH * SEQ;

  const int rq = qt * 64 + w4 * 16 + lo16;
  bf16x8 qf[2];
#pragma unroll
  for (int ks = 0; ks < 2; ks++)
    qf[ks] = *(const bf16x8*)&Q[base + (size_t)rq * D_MODEL + ks * 32 + quad * 8];

  bf16x8 onesf;
#pragma unroll
  for (int j = 0; j < 8; j++) onesf[j] = (bf16)1.0f;

  const floatx4 fz = {0.f, 0.f, 0.f, 0.f};
  floatx4 oacc[4];
  floatx4 lacc = fz;
#pragma unroll
  for (int i = 0; i < 4; i++) oacc[i] = fz;

  // staging indices: K chunk 128x64 (2 rows/thread), V chunk 64x128 (2 halves)
  const int kr = tid >> 3;        // 0..63
  const int kc = (tid & 7) * 8;

  bf16x8 kvp[2], vvp[2];
#pragma unroll
  for (int c2 = 0; c2 < 2; c2++) {
    kvp[c2] = *(const bf16x8*)&Kg[base + (size_t)(c2 * 64 + kr) * D_MODEL + kc];
    vvp[c2] = *(const bf16x8*)&Vt[baset + (size_t)kr * SEQ + c2 * 64 + kc];
  }

  for (int c = 0; c < n; c++) {
    const int j0 = c * 128;
    __syncthreads();
#pragma unroll
    for (int c2 = 0; c2 < 2; c2++) {
      *(bf16x8*)&Ks[(c2 * 64 + kr) * LPK + kc] = kvp[c2];
      *(bf16x8*)&VTs[kr * LPV + c2 * 64 + kc] = vvp[c2];
    }
    __syncthreads();

    if (c + 1 < n) {
      const int j1 = j0 + 128;
#pragma unroll
      for (int c2 = 0; c2 < 2; c2++) {
        kvp[c2] = *(const bf16x8*)&Kg[base + (size_t)(j1 + c2 * 64 + kr) * D_MODEL + kc];
        vvp[c2] = *(const bf16x8*)&Vt[baset + (size_t)kr * SEQ + j1 + c2 * 64 + kc];
      }
    }

    // QK^T (swapped: S^T in regs, lane holds P[k=n4*16+quad*4+r][q=lo16])
    floatx4 sacc[4];
#pragma unroll
    for (int n4 = 0; n4 < 4; n4++) sacc[n4] = fz;
#pragma unroll
    for (int n4 = 0; n4 < 4; n4++) {
      const int rk = g * 64 + n4 * 16 + lo16;
#pragma unroll
      for (int ks = 0; ks < 2; ks++) {
        bf16x8 kf = *(const bf16x8*)&Ks[rk * LPK + ks * 32 + quad * 8];
        sacc[n4] = __builtin_amdgcn_mfma_f32_16x16x32_bf16(kf, qf[ks], sacc[n4], 0, 0, 0);
      }
    }

    // softmax: p = 2^(s*0.18033688 - 17.3123405) (shift-invariant), pack to
    // bf16 words wv[n4][p] = (P[k=16n4+4q+2p], P[k=..+1]) for this lane.
    u32 wv[4][2];
    if (c == n - 1) {
      const int myq = rq;
#pragma unroll
      for (int n4 = 0; n4 < 4; n4++) {
        float e[4];
#pragma unroll
        for (int r = 0; r < 4; r++) {
          const int kvb = j0 + g * 64 + n4 * 16 + quad * 4 + r;
          const float ev = __builtin_amdgcn_exp2f(fmaf(sacc[n4][r], 0.18033688f, -17.3123405f));
          e[r] = (kvb > myq) ? 0.f : ev;
        }
        asm("v_cvt_pk_bf16_f32 %0, %1, %2" : "=v"(wv[n4][0]) : "v"(e[0]), "v"(e[1]));
        asm("v_cvt_pk_bf16_f32 %0, %1, %2" : "=v"(wv[n4][1]) : "v"(e[2]), "v"(e[3]));
      }
    } else {
#pragma unroll
      for (int n4 = 0; n4 < 4; n4++) {
        float e[4];
#pragma unroll
        for (int r = 0; r < 4; r++)
          e[r] = __builtin_amdgcn_exp2f(fmaf(sacc[n4][r], 0.18033688f, -17.3123405f));
        asm("v_cvt_pk_bf16_f32 %0, %1, %2" : "=v"(wv[n4][0]) : "v"(e[0]), "v"(e[1]));
        asm("v_cvt_pk_bf16_f32 %0, %1, %2" : "=v"(wv[n4][1]) : "v"(e[2]), "v"(e[3]));
      }
    }

    // in-register transpose to PV A-fragment: word(n4,p)@quad s must land at
    // dest quad t=2*(n4&1)+(s>>1), slot 2*(s&1)+p, half ks=n4>>1.
    // permlane32_swap then permlane16_swap on (w[2ks][p], w[2ks+1][p])
    // yields (slot p, slot 2+p) simultaneously.
#pragma unroll
    for (int ks = 0; ks < 2; ks++) {
      u32 a0 = wv[2 * ks][0], b0 = wv[2 * ks + 1][0];
      u32 a1 = wv[2 * ks][1], b1 = wv[2 * ks + 1][1];
      asm("v_permlane32_swap_b32 %0, %1" : "+v"(a0), "+v"(b0));
      asm("v_permlane16_swap_b32 %0, %1" : "+v"(a0), "+v"(b0));
      asm("v_permlane32_swap_b32 %0, %1" : "+v"(a1), "+v"(b1));
      asm("v_permlane16_swap_b32 %0, %1" : "+v"(a1), "+v"(b1));
      u32x4 fw = {a0, a1, b0, b1};
      const bf16x8 pf = __builtin_bit_cast(bf16x8, fw);
#pragma unroll
      for (int dt = 0; dt < 4; dt++) {
        bf16x8 vf = *(const bf16x8*)&VTs[(dt * 16 + lo16) * LPV + g * 64 + ks * 32 + quad * 8];
        oacc[dt] = __builtin_amdgcn_mfma_f32_16x16x32_bf16(pf, vf, oacc[dt], 0, 0, 0);
      }
      lacc = __builtin_amdgcn_mfma_f32_16x16x32_bf16(pf, onesf, lacc, 0, 0, 0);
    }
  }

  // epilogue: combine kv-half partials (additive; fixed shift).  Es aliases
  // the staging LDS, so drain all loop-phase LDS reads first.  Stride 21
  // floats: gcd(21,32)=1 -> 2 lanes/bank, conflict-free.
  __syncthreads();
  if (g == 1) {
    float* e = &Es[(w4 * 64 + lane) * 21];
#pragma unroll
    for (int dt = 0; dt < 4; dt++)
#pragma unroll
      for (int r = 0; r < 4; r++) e[dt * 4 + r] = oacc[dt][r];
#pragma unroll
    for (int r = 0; r < 4; r++) e[16 + r] = lacc[r];
  }
  __syncthreads();
  if (g == 0) {
    const float* e = &Es[(w4 * 64 + lane) * 21];
#pragma unroll
    for (int dt = 0; dt < 4; dt++)
#pragma unroll
      for (int r = 0; r < 4; r++) oacc[dt][r] += e[dt * 4 + r];
#pragma unroll
    for (int r = 0; r < 4; r++) lacc[r] += e[16 + r];

#pragma unroll
    for (int r = 0; r < 4; r++) {
      const float inv = 1.0f / lacc[r];
      const int row = qt * 64 + w4 * 16 + quad * 4 + r;
#pragma unroll
      for (int dt = 0; dt < 4; dt++)
        O[base + (size_t)row * D_MODEL + dt * 16 + lo16] = (bf16)(oacc[dt][r] * inv);
    }
  }
}

extern "C" void kernel_launch(void* const* d_in, const int* in_sizes, int n_in,
                              void* d_out, int out_size, void* d_ws, size_t ws_size,
                              hipStream_t stream) {
  const float* X  = (const float*)d_in[0];
  const float* Wq = (const float*)d_in[1];
  const float* Wk = (const float*)d_in[2];
  const float* Wv = (const float*)d_in[3];
  const float* Wo = (const float*)d_in[4];
  float* out = (float*)d_out;

  bf16* cvt = (bf16*)d_ws;
  bf16* Xb  = cvt;
  bf16* Wqb = cvt + XELEMS;       // Wq|Wk|Wv contiguous => concat [3072x1024]
  bf16* Wob = Wqb + 3 * WELEMS;
  bf16* Qb  = cvt + CVT_ELEMS;
  bf16* Kb  = Qb + XELEMS;
  bf16* Vtb = Kb + XELEMS;        // [B][H][DH][SEQ]
  bf16* Ob  = Vtb + XELEMS;

  dim3 blk(256);
  cvt_f32_bf16<<<dim3((u32)(CVT_ELEMS / (256 * 8))), blk, 0, stream>>>(
      X, Wq, Wk, Wv, Wo, cvt);
  gemm_qkv<<<dim3(24, 16), dim3(512), 0, stream>>>(Xb, Wqb, Qb, Kb, Vtb);
  attn_causal<<<dim3(32, NHEADS, BATCH), dim3(512), 0, stream>>>(Qb, Kb, Vtb, Ob);
  gemm_o<<<dim3(8, 64), blk, 0, stream>>>(Ob, Wob, out);
}

// Round 4
// 168.312 us; speedup vs baseline: 1.1512x; 1.0901x over previous
//
#include <hip/hip_runtime.h>
#include <hip/hip_bf16.h>
#include <stdint.h>
#include <type_traits>

typedef __bf16 bf16;
typedef __bf16 bf16x4 __attribute__((ext_vector_type(4)));
typedef __bf16 bf16x8 __attribute__((ext_vector_type(8)));
typedef float floatx4 __attribute__((ext_vector_type(4)));
typedef unsigned int u32;
typedef u32 u32x4 __attribute__((ext_vector_type(4)));

#define D_MODEL 1024
#define SEQ 2048
#define NHEADS 16
#define DH 64
#define BATCH 2
#define MROWS (BATCH * SEQ)  // 4096

#define XELEMS ((size_t)MROWS * D_MODEL)
#define WELEMS ((size_t)D_MODEL * D_MODEL)
#define CVT_ELEMS (XELEMS + 4 * WELEMS)

__device__ __forceinline__ void gload_lds16(const void* g, void* l) {
  __builtin_amdgcn_global_load_lds(
      (const __attribute__((address_space(1))) u32*)g,
      (__attribute__((address_space(3))) u32*)l, 16, 0, 0);
}

// ---------------------------------------------------------------------------
// One-shot f32 -> bf16 convert of X + 4 weights (~57 MB traffic, mem-bound).
// ---------------------------------------------------------------------------
__global__ __launch_bounds__(256) void cvt_f32_bf16(
    const float* __restrict__ s0, const float* __restrict__ s1,
    const float* __restrict__ s2, const float* __restrict__ s3,
    const float* __restrict__ s4, bf16* __restrict__ dst) {
  const size_t i = ((size_t)blockIdx.x * 256 + threadIdx.x) * 8;
  const float* src;
  size_t off;
  if (i < XELEMS) {
    src = s0; off = i;
  } else {
    const size_t j = i - XELEMS;
    const int r = (int)(j / WELEMS);
    src = (r == 0) ? s1 : (r == 1) ? s2 : (r == 2) ? s3 : s4;
    off = j - (size_t)r * WELEMS;
  }
  floatx4 f0 = *(const floatx4*)&src[off];
  floatx4 f1 = *(const floatx4*)&src[off + 4];
  bf16x8 o;
#pragma unroll
  for (int j = 0; j < 4; j++) { o[j] = (bf16)f0[j]; o[4 + j] = (bf16)f1[j]; }
  *(bf16x8*)&dst[i] = o;
}

// ---------------------------------------------------------------------------
// Merged QKV GEMM v2 (unchanged): single GEMM over concatenated
// W = [Wq|Wk|Wv] (3072x1024).  BM=256 x BN=128, BK=64, 8 waves, 3-slot LDS
// ring staged two K-tiles ahead with counted vmcnt(6) across raw barriers.
// ---------------------------------------------------------------------------
#define QKV_ASLOT (256 * 64)            // 16384 elems = 32 KB
#define QKV_SLOT  (256 * 64 + 128 * 64) // 24576 elems = 48 KB

__global__ __launch_bounds__(512) void gemm_qkv(
    const bf16* __restrict__ A, const bf16* __restrict__ W,
    bf16* __restrict__ Qo, bf16* __restrict__ Ko, bf16* __restrict__ Vto) {
  __shared__ bf16 sm[3 * QKV_SLOT];     // 147456 B

  const int tid = threadIdx.x;
  const int lane = tid & 63;
  const int w = tid >> 6;        // 0..7
  const int lo16 = lane & 15;
  const int quad = lane >> 4;
  const int wy = w >> 1;         // 0..3 : 64-row band of the 256-row tile
  const int wx = w & 1;          // 0..1 : 64-col band of the 128-col tile

  const int n0 = blockIdx.x * 128;   // 0..2944 (concat feature dim, 3072)
  const int m0 = blockIdx.y * 256;   // token-row tile

  const int sl = lane >> 3;
  const int sc = ((lane & 7) ^ sl) * 8;   // pre-swizzled global column

  const floatx4 fz = {0.f, 0.f, 0.f, 0.f};
  floatx4 acc[4][4];
#pragma unroll
  for (int i = 0; i < 4; i++)
#pragma unroll
    for (int j = 0; j < 4; j++) acc[i][j] = fz;

  auto stage = [&](int t, int s) {
    bf16* As = &sm[s * QKV_SLOT];
    bf16* Bs = As + QKV_ASLOT;
    const int k0 = t * 64;
#pragma unroll
    for (int i = 0; i < 4; i++) {
      const int seg = w * 4 + i;              // 0..31 (256 A rows)
      const int row = seg * 8 + sl;
      gload_lds16(&A[(size_t)(m0 + row) * 1024 + k0 + sc], &As[seg * 512]);
    }
#pragma unroll
    for (int i = 0; i < 2; i++) {
      const int seg = w * 2 + i;              // 0..15 (128 W rows)
      const int row = seg * 8 + sl;
      gload_lds16(&W[(size_t)(n0 + row) * 1024 + k0 + sc], &Bs[seg * 512]);
    }
  };

  auto compute = [&](int s, auto vt) {
    constexpr bool VT = decltype(vt)::value;
    const bf16* As = &sm[s * QKV_SLOT];
    const bf16* Bs = As + QKV_ASLOT;
#pragma unroll
    for (int kk = 0; kk < 64; kk += 32) {
      bf16x8 af[4], bfr[4];
      const int cc = (kk >> 3) + quad;
#pragma unroll
      for (int t = 0; t < 4; t++) {
        const int ra = wy * 64 + t * 16 + lo16;   // 0..255
        const int rb = wx * 64 + t * 16 + lo16;   // 0..127
        af[t]  = *(const bf16x8*)&As[ra * 64 + ((cc ^ (ra & 7)) << 3)];
        bfr[t] = *(const bf16x8*)&Bs[rb * 64 + ((cc ^ (rb & 7)) << 3)];
      }
#pragma unroll
      for (int mt = 0; mt < 4; mt++)
#pragma unroll
        for (int nt = 0; nt < 4; nt++) {
          if constexpr (VT)
            acc[mt][nt] = __builtin_amdgcn_mfma_f32_16x16x32_bf16(bfr[nt], af[mt], acc[mt][nt], 0, 0, 0);
          else
            acc[mt][nt] = __builtin_amdgcn_mfma_f32_16x16x32_bf16(af[mt], bfr[nt], acc[mt][nt], 0, 0, 0);
        }
    }
  };

  auto step = [&](int t, int s, auto vt) {
    if (t + 2 < 16) stage(t + 2, (t + 2) % 3);
    compute(s, vt);
    if (t < 15) {
      if (t + 2 < 16) { asm volatile("s_waitcnt vmcnt(6)" ::: "memory"); }
      else            { asm volatile("s_waitcnt vmcnt(0)" ::: "memory"); }
      __builtin_amdgcn_s_barrier();
    }
  };

  auto mainloop = [&](auto vt) {
    stage(0, 0);
    stage(1, 1);
    asm volatile("s_waitcnt vmcnt(6)" ::: "memory");
    __builtin_amdgcn_s_barrier();
    for (int tb = 0; tb < 15; tb += 3) {
      step(tb + 0, 0, vt);
      step(tb + 1, 1, vt);
      step(tb + 2, 2, vt);
    }
    step(15, 0, vt);   // tail: no wait/barrier
  };
  if (n0 >= 2048) mainloop(std::true_type{}); else mainloop(std::false_type{});

  if (n0 < 2048) {
    bf16* C = (n0 < 1024) ? Qo : Ko;
    const int nc = (n0 < 1024) ? n0 : n0 - 1024;
#pragma unroll
    for (int mt = 0; mt < 4; mt++)
#pragma unroll
      for (int nt = 0; nt < 4; nt++)
#pragma unroll
        for (int r = 0; r < 4; r++) {
          const int row = m0 + wy * 64 + mt * 16 + quad * 4 + r;
          const int col = nc + wx * 64 + nt * 16 + lo16;
          C[(size_t)row * D_MODEL + col] = (bf16)acc[mt][nt][r];
        }
  } else {
    const int nv = n0 - 2048;
#pragma unroll
    for (int mt = 0; mt < 4; mt++)
#pragma unroll
      for (int nt = 0; nt < 4; nt++)
#pragma unroll
        for (int r = 0; r < 4; r++) {
          const int feat = nv + wx * 64 + nt * 16 + quad * 4 + r;
          const int tok  = m0 + wy * 64 + mt * 16 + lo16;
          const int hh = feat >> 6, dd = feat & 63;
          const int bb = tok >> 11, ss = tok & 2047;
          Vto[(size_t)((bb * NHEADS + hh) * DH + dd) * SEQ + ss] = (bf16)acc[mt][nt][r];
        }
  }
}

// ---------------------------------------------------------------------------
// O-projection GEMM (unchanged): 64x128 tile, BK=128 as two BK=64 halves,
// XOR swizzle, f32 out.
// ---------------------------------------------------------------------------
__global__ __launch_bounds__(256) void gemm_o(
    const bf16* __restrict__ A, const bf16* __restrict__ W,
    float* __restrict__ C) {
  __shared__ bf16 As[2 * 64 * 64];
  __shared__ bf16 Bs[2 * 128 * 64];

  const int tid = threadIdx.x;
  const int lane = tid & 63;
  const int w = tid >> 6;
  const int lo16 = lane & 15;
  const int quad = lane >> 4;
  const int wy = w >> 1, wx = w & 1;

  const int m0 = blockIdx.y * 64;
  const int n0 = blockIdx.x * 128;

  const int sl = lane >> 3;
  const int sc = ((lane & 7) ^ sl) * 8;

  const floatx4 fz = {0.f, 0.f, 0.f, 0.f};
  floatx4 acc[2][4];
#pragma unroll
  for (int i = 0; i < 2; i++)
#pragma unroll
    for (int j = 0; j < 4; j++) acc[i][j] = fz;

  for (int k0 = 0; k0 < 1024; k0 += 128) {
    __syncthreads();
#pragma unroll
    for (int kh = 0; kh < 2; kh++) {
#pragma unroll
      for (int i = 0; i < 2; i++) {
        const int seg = i * 4 + w;
        const int row = seg * 8 + sl;
        gload_lds16(&A[(size_t)(m0 + row) * 1024 + k0 + kh * 64 + sc],
                    &As[kh * 4096 + seg * 512]);
      }
#pragma unroll
      for (int i = 0; i < 4; i++) {
        const int seg = i * 4 + w;
        const int row = seg * 8 + sl;
        gload_lds16(&W[(size_t)(n0 + row) * 1024 + k0 + kh * 64 + sc],
                    &Bs[kh * 8192 + seg * 512]);
      }
    }
    __syncthreads();

#pragma unroll
    for (int kk = 0; kk < 128; kk += 32) {
      const int kh = kk >> 6;
      const int cc = ((kk & 63) >> 3) + quad;
      bf16x8 af[2], bfr[4];
#pragma unroll
      for (int t = 0; t < 2; t++) {
        const int ra = wy * 32 + t * 16 + lo16;
        af[t] = *(const bf16x8*)&As[kh * 4096 + ra * 64 + ((cc ^ (ra & 7)) << 3)];
      }
#pragma unroll
      for (int t = 0; t < 4; t++) {
        const int rb = wx * 64 + t * 16 + lo16;
        bfr[t] = *(const bf16x8*)&Bs[kh * 8192 + rb * 64 + ((cc ^ (rb & 7)) << 3)];
      }
#pragma unroll
      for (int mt = 0; mt < 2; mt++)
#pragma unroll
        for (int nt = 0; nt < 4; nt++)
          acc[mt][nt] = __builtin_amdgcn_mfma_f32_16x16x32_bf16(af[mt], bfr[nt], acc[mt][nt], 0, 0, 0);
    }
  }

#pragma unroll
  for (int mt = 0; mt < 2; mt++)
#pragma unroll
    for (int nt = 0; nt < 4; nt++)
#pragma unroll
      for (int r = 0; r < 4; r++) {
        const int row = m0 + wy * 32 + mt * 16 + quad * 4 + r;
        const int col = n0 + wx * 64 + nt * 16 + lo16;
        C[(size_t)row * D_MODEL + col] = acc[mt][nt][r];
      }
}

// ---------------------------------------------------------------------------
// Causal flash attention v10: v7's paired-q-set structure (grid 16x16x2,
// blocks take q-tiles (x, 31-x) -> perfectly balanced ~17 computes/block,
// 2 computes per staged chunk) + v9's in-register P (cvt_pk + permlane
// transpose, no Ps LDS).  No min-waves clamp: v7's forced (512,4) caused
// ~22MB/dispatch scratch spill (WRITE_SIZE 30720 vs 8192 KB); dual-set
// state (~84 persistent VGPR) must allocate freely -- grid gives 2
// blocks/CU regardless.  Epilogue combine stride 41 (odd -> conflict-free),
// smem = 256*41*4 = 41984 B.
// ---------------------------------------------------------------------------
#define LPK 72    // Ks row stride (bf16): 128 rows
#define LPV 136   // VTs row stride (bf16): 64 rows x 128 kv cols

__global__ __launch_bounds__(512) void attn_causal(
    const bf16* __restrict__ Q, const bf16* __restrict__ Kg,
    const bf16* __restrict__ Vt, bf16* __restrict__ O) {
  __shared__ __align__(16) char smem[41984];
  bf16* Ks  = (bf16*)smem;              // 128*72*2  = 18432 B
  bf16* VTs = (bf16*)(smem + 18432);    // 64*136*2  = 17408 B
  float* Es = (float*)smem;             // epilogue alias: 256*41*4 = 41984 B

  const int tid = threadIdx.x;
  const int lane = tid & 63;
  const int wid = tid >> 6;      // 0..7
  const int g = wid >> 2;        // kv-half of the 128-chunk
  const int w4 = wid & 3;        // q-quarter
  const int lo16 = lane & 15;
  const int quad = lane >> 4;

  const int x = blockIdx.x;      // 0..15
  const int qtA = x;
  const int qtB = 31 - x;
  const int nA = (qtA + 2) >> 1; // chunks for A-set
  const int nB = (qtB + 2) >> 1; // chunks for B-set (= staging count, >= nA)
  const int h = blockIdx.y;
  const int b = blockIdx.z;
  const size_t base  = (size_t)b * SEQ * D_MODEL + (size_t)h * DH;
  const size_t baset = (size_t)(b * NHEADS + h) * DH * SEQ;

  const int rA = qtA * 64 + w4 * 16 + lo16;
  const int rB = qtB * 64 + w4 * 16 + lo16;
  bf16x8 qfA[2], qfB[2];
#pragma unroll
  for (int ks = 0; ks < 2; ks++) {
    qfA[ks] = *(const bf16x8*)&Q[base + (size_t)rA * D_MODEL + ks * 32 + quad * 8];
    qfB[ks] = *(const bf16x8*)&Q[base + (size_t)rB * D_MODEL + ks * 32 + quad * 8];
  }

  bf16x8 onesf;
#pragma unroll
  for (int j = 0; j < 8; j++) onesf[j] = (bf16)1.0f;

  const floatx4 fz = {0.f, 0.f, 0.f, 0.f};
  floatx4 oA[4], oB[4];
  floatx4 lA = fz, lB = fz;
#pragma unroll
  for (int i = 0; i < 4; i++) { oA[i] = fz; oB[i] = fz; }

  // staging indices: K chunk 128x64 (2 rows/thread), V chunk 64x128 (2 halves)
  const int kr = tid >> 3;        // 0..63
  const int kc = (tid & 7) * 8;

  bf16x8 kvp[2], vvp[2];
#pragma unroll
  for (int c2 = 0; c2 < 2; c2++) {
    kvp[c2] = *(const bf16x8*)&Kg[base + (size_t)(c2 * 64 + kr) * D_MODEL + kc];
    vvp[c2] = *(const bf16x8*)&Vt[baset + (size_t)kr * SEQ + c2 * 64 + kc];
  }

  for (int c = 0; c < nB; c++) {
    const int j0 = c * 128;
    __syncthreads();
#pragma unroll
    for (int c2 = 0; c2 < 2; c2++) {
      *(bf16x8*)&Ks[(c2 * 64 + kr) * LPK + kc] = kvp[c2];
      *(bf16x8*)&VTs[kr * LPV + c2 * 64 + kc] = vvp[c2];
    }
    __syncthreads();

    if (c + 1 < nB) {
      const int j1 = j0 + 128;
#pragma unroll
      for (int c2 = 0; c2 < 2; c2++) {
        kvp[c2] = *(const bf16x8*)&Kg[base + (size_t)(j1 + c2 * 64 + kr) * D_MODEL + kc];
        vvp[c2] = *(const bf16x8*)&Vt[baset + (size_t)kr * SEQ + j1 + c2 * 64 + kc];
      }
    }

    // one kv-half compute for one q-set over this 128-chunk
    auto compute = [&](int q0s, const bf16x8* qf, floatx4* oacc, floatx4& lacc,
                       bool diag) {
      // QK^T (swapped: S^T in regs, lane holds P[k=n4*16+quad*4+r][q=lo16])
      floatx4 sacc[4];
#pragma unroll
      for (int n4 = 0; n4 < 4; n4++) sacc[n4] = fz;
#pragma unroll
      for (int n4 = 0; n4 < 4; n4++) {
        const int rk = g * 64 + n4 * 16 + lo16;
#pragma unroll
        for (int ks = 0; ks < 2; ks++) {
          bf16x8 kf = *(const bf16x8*)&Ks[rk * LPK + ks * 32 + quad * 8];
          sacc[n4] = __builtin_amdgcn_mfma_f32_16x16x32_bf16(kf, qf[ks], sacc[n4], 0, 0, 0);
        }
      }

      // softmax: p = 2^(s*0.18033688 - 17.3123405) (shift-invariant), pack
      // to bf16 words wv[n4][p] = (P[k=16n4+4q+2p], P[k=..+1]).
      u32 wv[4][2];
      if (diag) {
        const int myq = q0s + w4 * 16 + lo16;
#pragma unroll
        for (int n4 = 0; n4 < 4; n4++) {
          float e[4];
#pragma unroll
          for (int r = 0; r < 4; r++) {
            const int kvb = j0 + g * 64 + n4 * 16 + quad * 4 + r;
            const float ev = __builtin_amdgcn_exp2f(fmaf(sacc[n4][r], 0.18033688f, -17.3123405f));
            e[r] = (kvb > myq) ? 0.f : ev;
          }
          asm("v_cvt_pk_bf16_f32 %0, %1, %2" : "=v"(wv[n4][0]) : "v"(e[0]), "v"(e[1]));
          asm("v_cvt_pk_bf16_f32 %0, %1, %2" : "=v"(wv[n4][1]) : "v"(e[2]), "v"(e[3]));
        }
      } else {
#pragma unroll
        for (int n4 = 0; n4 < 4; n4++) {
          float e[4];
#pragma unroll
          for (int r = 0; r < 4; r++)
            e[r] = __builtin_amdgcn_exp2f(fmaf(sacc[n4][r], 0.18033688f, -17.3123405f));
          asm("v_cvt_pk_bf16_f32 %0, %1, %2" : "=v"(wv[n4][0]) : "v"(e[0]), "v"(e[1]));
          asm("v_cvt_pk_bf16_f32 %0, %1, %2" : "=v"(wv[n4][1]) : "v"(e[2]), "v"(e[3]));
        }
      }

      // in-register transpose to PV A-fragment: permlane32_swap +
      // permlane16_swap on (wv[2ks][p], wv[2ks+1][p]); both outputs used.
#pragma unroll
      for (int ks = 0; ks < 2; ks++) {
        u32 a0 = wv[2 * ks][0], b0 = wv[2 * ks + 1][0];
        u32 a1 = wv[2 * ks][1], b1 = wv[2 * ks + 1][1];
        asm("v_permlane32_swap_b32 %0, %1" : "+v"(a0), "+v"(b0));
        asm("v_permlane16_swap_b32 %0, %1" : "+v"(a0), "+v"(b0));
        asm("v_permlane32_swap_b32 %0, %1" : "+v"(a1), "+v"(b1));
        asm("v_permlane16_swap_b32 %0, %1" : "+v"(a1), "+v"(b1));
        u32x4 fw = {a0, a1, b0, b1};
        const bf16x8 pf = __builtin_bit_cast(bf16x8, fw);
#pragma unroll
        for (int dt = 0; dt < 4; dt++) {
          bf16x8 vf = *(const bf16x8*)&VTs[(dt * 16 + lo16) * LPV + g * 64 + ks * 32 + quad * 8];
          oacc[dt] = __builtin_amdgcn_mfma_f32_16x16x32_bf16(pf, vf, oacc[dt], 0, 0, 0);
        }
        lacc = __builtin_amdgcn_mfma_f32_16x16x32_bf16(pf, onesf, lacc, 0, 0, 0);
      }
    };

    compute(qtB * 64, qfB, oB, lB, c == nB - 1);
    if (c < nA) compute(qtA * 64, qfA, oA, lA, c == nA - 1);
  }

  // epilogue: combine kv-half partials (additive; fixed shift).  Es aliases
  // the staging LDS, so drain all loop-phase LDS reads first.  Stride 41
  // floats: gcd(41,32)=1 -> conflict-free.
  __syncthreads();
  if (g == 1) {
    float* e = &Es[(w4 * 64 + lane) * 41];
#pragma unroll
    for (int dt = 0; dt < 4; dt++)
#pragma unroll
      for (int r = 0; r < 4; r++) e[dt * 4 + r] = oA[dt][r];
#pragma unroll
    for (int r = 0; r < 4; r++) e[16 + r] = lA[r];
#pragma unroll
    for (int dt = 0; dt < 4; dt++)
#pragma unroll
      for (int r = 0; r < 4; r++) e[20 + dt * 4 + r] = oB[dt][r];
#pragma unroll
    for (int r = 0; r < 4; r++) e[36 + r] = lB[r];
  }
  __syncthreads();
  if (g == 0) {
    const float* e = &Es[(w4 * 64 + lane) * 41];
#pragma unroll
    for (int dt = 0; dt < 4; dt++)
#pragma unroll
      for (int r = 0; r < 4; r++) { oA[dt][r] += e[dt * 4 + r]; oB[dt][r] += e[20 + dt * 4 + r]; }
#pragma unroll
    for (int r = 0; r < 4; r++) { lA[r] += e[16 + r]; lB[r] += e[36 + r]; }

    auto finish = [&](int q0s, floatx4* oacc, floatx4 lacc) {
#pragma unroll
      for (int r = 0; r < 4; r++) {
        const float inv = 1.0f / lacc[r];
        const int row = q0s + w4 * 16 + quad * 4 + r;
#pragma unroll
        for (int dt = 0; dt < 4; dt++)
          O[base + (size_t)row * D_MODEL + dt * 16 + lo16] = (bf16)(oacc[dt][r] * inv);
      }
    };
    finish(qtA * 64, oA, lA);
    finish(qtB * 64, oB, lB);
  }
}

extern "C" void kernel_launch(void* const* d_in, const int* in_sizes, int n_in,
                              void* d_out, int out_size, void* d_ws, size_t ws_size,
                              hipStream_t stream) {
  const float* X  = (const float*)d_in[0];
  const float* Wq = (const float*)d_in[1];
  const float* Wk = (const float*)d_in[2];
  const float* Wv = (const float*)d_in[3];
  const float* Wo = (const float*)d_in[4];
  float* out = (float*)d_out;

  bf16* cvt = (bf16*)d_ws;
  bf16* Xb  = cvt;
  bf16* Wqb = cvt + XELEMS;       // Wq|Wk|Wv contiguous => concat [3072x1024]
  bf16* Wob = Wqb + 3 * WELEMS;
  bf16* Qb  = cvt + CVT_ELEMS;
  bf16* Kb  = Qb + XELEMS;
  bf16* Vtb = Kb + XELEMS;        // [B][H][DH][SEQ]
  bf16* Ob  = Vtb + XELEMS;

  dim3 blk(256);
  cvt_f32_bf16<<<dim3((u32)(CVT_ELEMS / (256 * 8))), blk, 0, stream>>>(
      X, Wq, Wk, Wv, Wo, cvt);
  gemm_qkv<<<dim3(24, 16), dim3(512), 0, stream>>>(Xb, Wqb, Qb, Kb, Vtb);
  attn_causal<<<dim3(16, NHEADS, BATCH), dim3(512), 0, stream>>>(Qb, Kb, Vtb, Ob);
  gemm_o<<<dim3(8, 64), blk, 0, stream>>>(Ob, Wob, out);
}